// Round 5
// baseline (391.495 us; speedup 1.0000x reference)
//
#include <hip/hip_runtime.h>
#include <hip/hip_bf16.h>

// AttentionWithContext: out[b,f] = sum_t a[b,t] x[b,t,f],
//   a = exp(ait)/(sum_t exp(ait) + 1e-7),  ait = tanh(x@W + bias) . u
// R5: R4's async-DMA double-buffer pipeline at 2x wave parallelism.
// 512-thread blocks (8 waves), 2 blocks/CU -> 16 waves/CU, 4 waves/SIMD.
// Wave owns 32 g-columns -> Wt A-fragments = 64 VGPRs (fits 128-VGPR budget
// at launch_bounds(512,4)). x fp32 tiles staged via global_load_lds
// (zero-VGPR DMA), raw s_barrier + s_waitcnt vmcnt(4) keeps next tile's
// DMAs in flight across the barrier. bias/-2u in LDS. x read from HBM once.

#define BB 128
#define TT 2048
#define FF 256
#define TQ 32                  // timesteps per tile
#define NT 16                  // tiles per block
#define NBLK (BB * (TT / (TQ * NT)))   // 128 * 4 = 512 blocks = 2/CU
#define RS 260                 // LDS row stride in fp32 (256 data + 4 pad = 1040 B)

// s_waitcnt imms: vmcnt[3:0]|[15:14], expcnt[6:4], lgkmcnt[11:8]
#define W_VM4   0x0F74         // vmcnt(4),  lgkm/exp no-wait
#define W_VM0   0x0F70         // vmcnt(0),  lgkm/exp no-wait
#define W_LGKM0 0xC07F         // lgkmcnt(0), vm/exp no-wait

using bf16x8 = __attribute__((ext_vector_type(8))) short;
using f32x4  = __attribute__((ext_vector_type(4))) float;

typedef __attribute__((address_space(1))) const void* as1cv;
typedef __attribute__((address_space(3))) void* as3v;

__device__ __forceinline__ unsigned short f2bf(float f) {
  union { float f; unsigned u; } v; v.f = f;
  unsigned r = v.u + 0x7fffu + ((v.u >> 16) & 1u);   // RNE
  return (unsigned short)(r >> 16);
}
__device__ __forceinline__ unsigned pk2bf(float a, float b) {
  __hip_bfloat162 h = __float22bfloat162_rn(make_float2(a, b));  // v_cvt_pk_bf16_f32
  union { __hip_bfloat162 h; unsigned u; } v; v.h = h;
  return v.u;
}

template <int IMM>
__device__ __forceinline__ void wait_barrier() {
  asm volatile("" ::: "memory");
  __builtin_amdgcn_s_waitcnt(IMM);
  __builtin_amdgcn_s_barrier();
  asm volatile("" ::: "memory");
}

// ---------------- prep: Wt[g][k] = bf16(W[k][g]); zero num+denom ----------------
__global__ void prep(const float* __restrict__ W, unsigned short* __restrict__ Wt,
                     float* __restrict__ zr) {
  int i = blockIdx.x * 256 + threadIdx.x;
  if (i < FF * FF) {
    int f = i >> 8, g = i & 255;             // coalesced read of W[f][g]
    Wt[g * FF + f] = f2bf(W[i]);
  }
  int j = i - FF * FF;
  if (j >= 0 && j < BB * FF + BB) zr[j] = 0.f;
}

// ---------------- main fused kernel ----------------
__global__ __launch_bounds__(512, 4)   // 8 waves/block, 2 blocks/CU, 128 VGPR budget
void attn_main(const float* __restrict__ x, const unsigned short* __restrict__ Wt,
               const float* __restrict__ bias, const float* __restrict__ uvec,
               float* __restrict__ num, float* __restrict__ denom) {
  __shared__ float xb[2][TQ * RS];     // 2 x 33280 B fp32 staging
  __shared__ float part[8][TQ];        // per-wave g-partials of ait
  __shared__ float bu[512];            // [0:256) bias, [256:512) -2*u

  const int tid  = threadIdx.x;
  const int wave = tid >> 6;           // 0..7
  const int lane = tid & 63;
  const int q    = lane >> 4;          // quad
  const int ln   = lane & 15;
  const int b    = blockIdx.x >> 2;    // batch row
  const int seg  = blockIdx.x & 3;     // 512-t segment
  const float* xt = x + ((long)b * TT + (long)seg * (NT * TQ)) * FF;
  const int gbase = wave * 32;         // wave owns g in [32w, 32w+32)

  // ---- issue tile 0 staging DMAs first (4 rows/wave, 1 KB each) ----
  {
    const float* gp = xt + lane * 4;
    #pragma unroll
    for (int r = 0; r < 4; ++r) {
      int row = wave * 4 + r;
      __builtin_amdgcn_global_load_lds((as1cv)(const void*)(gp + row * FF),
                                       (as3v)(void*)(&xb[0][row * RS]), 16, 0, 0);
    }
  }

  if (tid < 256) { bu[tid] = bias[tid]; bu[256 + tid] = -2.f * uvec[tid]; }

  // ---- preload this wave's Wt A-fragments: 16 x 16B = 64 VGPRs ----
  bf16x8 afr[8][2];
  #pragma unroll
  for (int kk = 0; kk < 8; ++kk)
    #pragma unroll
    for (int gt = 0; gt < 2; ++gt)
      afr[kk][gt] = *(const bf16x8*)(Wt + (gbase + gt * 16 + ln) * FF + kk * 32 + q * 8);

  // su = sum of this lane's 8 u[g] (epilogue constant fold)
  float su = 0.f;
  #pragma unroll
  for (int gt = 0; gt < 2; ++gt)
    #pragma unroll
    for (int r = 0; r < 4; ++r)
      su += uvec[gbase + gt * 16 + q * 4 + r];

  f32x4 na = {0.f, 0.f, 0.f, 0.f};     // numerator accum, f = lane*4..+3
  float dacc = 0.f;                    // denom accum (wave0/lane0 valid)

  for (int it = 0; it < NT; ++it) {
    const int cur = it & 1;
    const float* buf = xb[cur];

    // ---- issue next tile's DMAs into the other buffer ----
    if (it + 1 < NT) {
      const float* gp = xt + (long)(it + 1) * TQ * FF + lane * 4;
      float* obuf = xb[cur ^ 1];
      #pragma unroll
      for (int r = 0; r < 4; ++r) {
        int row = wave * 4 + r;
        __builtin_amdgcn_global_load_lds((as1cv)(const void*)(gp + row * FF),
                                         (as3v)(void*)(&obuf[row * RS]), 16, 0, 0);
      }
      wait_barrier<W_VM4>();   // current tile's 4 DMAs done; next 4 stay in flight
    } else {
      wait_barrier<W_VM0>();
    }

    // ---- MFMA: C[g][t]; fp32->bf16 cvt at B-fragment build ----
    f32x4 acc[2][2];
    #pragma unroll
    for (int i = 0; i < 2; ++i) { acc[i][0] = (f32x4){0,0,0,0}; acc[i][1] = (f32x4){0,0,0,0}; }

    #pragma unroll
    for (int kk = 0; kk < 8; ++kk) {
      #pragma unroll
      for (int tt = 0; tt < 2; ++tt) {
        const float* p = &buf[(tt * 16 + ln) * RS + kk * 32 + q * 8];
        f32x4 v0 = *(const f32x4*)p;
        f32x4 v1 = *(const f32x4*)(p + 4);
        union { bf16x8 v; unsigned u[4]; } bb;
        bb.u[0] = pk2bf(v0.x, v0.y); bb.u[1] = pk2bf(v0.z, v0.w);
        bb.u[2] = pk2bf(v1.x, v1.y); bb.u[3] = pk2bf(v1.z, v1.w);
        #pragma unroll
        for (int gt = 0; gt < 2; ++gt)
          acc[gt][tt] = __builtin_amdgcn_mfma_f32_16x16x32_bf16(afr[kk][gt], bb.v, acc[gt][tt], 0, 0, 0);
      }
    }

    // ---- epilogue: partial ait = su_w + sum_g m2u[g]/(exp(2(C+bias))+1) ----
    #pragma unroll
    for (int tt = 0; tt < 2; ++tt) {
      float s = su;
      #pragma unroll
      for (int gt = 0; gt < 2; ++gt) {
        int g0 = gbase + gt * 16 + q * 4;
        f32x4 bi4 = *(const f32x4*)(&bu[g0]);
        f32x4 m24 = *(const f32x4*)(&bu[256 + g0]);
        #pragma unroll
        for (int r = 0; r < 4; ++r) {
          float vv = acc[gt][tt][r] + bi4[r];
          float e1 = __expf(2.f * vv) + 1.f;   // inf-safe tanh fold
          s += m24[r] * __fdividef(1.f, e1);
        }
      }
      s += __shfl_xor(s, 16, 64);              // reduce across quads
      s += __shfl_xor(s, 32, 64);
      if (lane < 16) part[wave][tt * 16 + lane] = s;
    }
    wait_barrier<W_LGKM0>();

    // ---- every wave: e[t] for t = lane&31 (redundant, broadcast-friendly) ----
    const int tl = lane & 31;
    float ait = part[0][tl] + part[1][tl] + part[2][tl] + part[3][tl]
              + part[4][tl] + part[5][tl] + part[6][tl] + part[7][tl];
    float e = __expf(ait);
    if (wave == 0) {
      float dp = (lane < 32) ? e : 0.f;
      dp += __shfl_xor(dp, 1, 64);  dp += __shfl_xor(dp, 2, 64);
      dp += __shfl_xor(dp, 4, 64);  dp += __shfl_xor(dp, 8, 64);
      dp += __shfl_xor(dp, 16, 64);
      dacc += dp;                              // lane 0 holds tile's denom partial
    }

    // ---- numerator: wave owns rows t = wave*4..+3; na += e[t]*x[t][lane*4..] ----
    #pragma unroll
    for (int i = 0; i < 4; ++i) {
      int t = wave * 4 + i;
      float ev = __shfl(e, t, 64);             // lane t (<32) holds e[t]
      f32x4 xv = *(const f32x4*)(&buf[t * RS + lane * 4]);
      na += xv * ev;
    }
    wait_barrier<W_LGKM0>();   // all reads of buf done before its DMA overwrite
  }

  // ---- cross-wave reduce numerator through LDS, then atomics ----
  __syncthreads();
  float* nred = &xb[0][0];                     // 8 x 256 floats = 8 KB
  *(f32x4*)(&nred[wave * 256 + lane * 4]) = na;
  __syncthreads();
  if (tid < 256) {
    float v = 0.f;
    #pragma unroll
    for (int w = 0; w < 8; ++w) v += nred[w * 256 + tid];
    atomicAdd(&num[b * FF + tid], v);
  }
  if (tid == 0) atomicAdd(&denom[b], dacc);
}

// ---------------- finalize: out = num / (denom + eps) ----------------
__global__ void finalize(const float* __restrict__ num, const float* __restrict__ denom,
                         float* __restrict__ out) {
  int i = blockIdx.x * 256 + threadIdx.x;      // 32768
  out[i] = num[i] / (denom[i >> 8] + 1e-7f);
}

extern "C" void kernel_launch(void* const* d_in, const int* in_sizes, int n_in,
                              void* d_out, int out_size, void* d_ws, size_t ws_size,
                              hipStream_t stream) {
  const float* x  = (const float*)d_in[0];
  const float* W  = (const float*)d_in[1];
  const float* bv = (const float*)d_in[2];
  const float* uv = (const float*)d_in[3];
  float* out = (float*)d_out;

  unsigned short* Wt = (unsigned short*)d_ws;                 // 131072 B
  float* num   = (float*)((char*)d_ws + FF * FF * 2);         // 131072 B
  float* denom = num + BB * FF;                               // 512 B

  prep<<<(FF * FF + BB * FF + BB + 255) / 256, 256, 0, stream>>>(W, Wt, num);
  attn_main<<<NBLK, 512, 0, stream>>>(x, Wt, bv, uv, num, denom);
  finalize<<<(BB * FF) / 256, 256, 0, stream>>>(num, denom, out);
}